// Round 9
// baseline (508.456 us; speedup 1.0000x reference)
//
#include <hip/hip_runtime.h>
#include <math.h>

#define B_  2
#define L_  2000
#define DM_ 256
#define DI_ 512
#define DS_ 16
#define NL_ 4
#define BL_ (B_*L_)     // 4000
#define BLP_ 4096       // rows padded to multiple of 64
#define NC_  125        // scan chunks == conv strips (CL=16)
#define CL_  16
#define NST_ (B_*DI_*DS_)   // 16384 scan states
#define NCONVB_ 250     // conv grid blocks
#define NPH2B_  32      // ph2 worker blocks (16384/512)

typedef unsigned short ushort_t;
typedef __attribute__((ext_vector_type(8))) short bf16x8;
typedef __attribute__((ext_vector_type(4))) float f32x4;

__device__ __forceinline__ float siluf(float x) { return x / (1.f + __expf(-x)); }
__device__ __forceinline__ ushort_t f2bf(float x) {
    unsigned int u = __float_as_uint(x);
    return (ushort_t)((u + 0x7FFFu + ((u >> 16) & 1u)) >> 16);
}
__device__ __forceinline__ float bf2f(ushort_t v) {
    return __uint_as_float(((unsigned int)v) << 16);
}

// ---- merged embed + layer-0 LN (blocks 0..BL_-1) + weight f2bf (rest) ----
__global__ __launch_bounds__(256) void embed_f2bf_kernel(
    const float* __restrict__ x, const float* __restrict__ biw,
    const float* __restrict__ bib, const float* __restrict__ ge,
    const float* __restrict__ me, const float* __restrict__ lnw,
    const float* __restrict__ lnb,
    float* __restrict__ h, ushort_t* __restrict__ aln,
    const float* __restrict__ s0, const float* __restrict__ s1,
    const float* __restrict__ s2, ushort_t* __restrict__ d0,
    ushort_t* __restrict__ d1, ushort_t* __restrict__ d2,
    int N0, int N1, int N2, unsigned int* __restrict__ cnt)
{
    if (blockIdx.x < BL_) {
        __shared__ float sm[8];
        int bl = blockIdx.x, d = threadIdx.x;
        int l = bl % L_;
        float v = x[bl]*biw[d] + bib[d] + ge[(size_t)l*DM_ + d] + me[d];
        h[(size_t)bl*DM_ + d] = v;
        float s = v, q = v*v;
        #pragma unroll
        for (int o = 32; o > 0; o >>= 1) {
            s += __shfl_down(s, o);
            q += __shfl_down(q, o);
        }
        if ((d & 63) == 0) { sm[d >> 6] = s; sm[4 + (d >> 6)] = q; }
        __syncthreads();
        float sum = sm[0]+sm[1]+sm[2]+sm[3];
        float ssq = sm[4]+sm[5]+sm[6]+sm[7];
        float mu  = sum * (1.f/DM_);
        float inv = rsqrtf(fmaxf(ssq*(1.f/DM_) - mu*mu, 0.f) + 1e-5f);
        aln[(size_t)bl*DM_ + d] = f2bf((v - mu)*inv*lnw[d] + lnb[d]);
    } else {
        if (blockIdx.x == BL_ && threadIdx.x < NL_)
            __hip_atomic_store(&cnt[threadIdx.x], 0u,
                               __ATOMIC_RELAXED, __HIP_MEMORY_SCOPE_AGENT);
        int i = (blockIdx.x - BL_)*256 + threadIdx.x;
        const float* s; ushort_t* d; int j;
        if (i < N0)           { s = s0; d = d0; j = i; }
        else if (i < N0+N1)   { s = s1; d = d1; j = i - N0; }
        else if (i < N0+N1+N2){ s = s2; d = d2; j = i - N0 - N1; }
        else return;
        float4 v = *(const float4*)(s + 4*j);
        ushort_t o[4] = {f2bf(v.x), f2bf(v.y), f2bf(v.z), f2bf(v.w)};
        *(ushort2*)(d + 4*j)     = *(ushort2*)&o[0];
        *(ushort2*)(d + 4*j + 2) = *(ushort2*)&o[2];
    }
}

// ---------------- pure bf16 MFMA GEMM: xz = aln * ipw^T (layer 0) ----------------
__global__ __launch_bounds__(256) void gemm_bf(
    const ushort_t* __restrict__ A, const ushort_t* __restrict__ W,
    ushort_t* __restrict__ C)
{
    __shared__ ushort_t a_s[128*64];
    __shared__ ushort_t b_s[128*64];
    const int r0 = blockIdx.x*128, c0 = blockIdx.y*128;
    const int tid = threadIdx.x;
    const int lane = tid & 63, w = tid >> 6;
    const int wm = (w & 1)*64, wn = (w >> 1)*64;
    const int qd = lane >> 4, l16 = lane & 15;
    f32x4 acc[4][4] = {};
    for (int kc = 0; kc < DM_; kc += 64) {
        #pragma unroll
        for (int q = 0; q < 4; q++) {
            int ch = tid + 256*q;
            int row = ch >> 3, col8 = (ch & 7)*8;
            *(bf16x8*)&a_s[row*64 + col8] =
                *(const bf16x8*)(A + (size_t)(r0 + row)*DM_ + kc + col8);
            *(bf16x8*)&b_s[row*64 + col8] =
                *(const bf16x8*)(W + (size_t)(c0 + row)*DM_ + kc + col8);
        }
        __syncthreads();
        #pragma unroll
        for (int ks = 0; ks < 2; ks++) {
            bf16x8 af[4], bf[4];
            #pragma unroll
            for (int i = 0; i < 4; i++)
                af[i] = *(const bf16x8*)&a_s[(wm + i*16 + l16)*64 + ks*32 + qd*8];
            #pragma unroll
            for (int j = 0; j < 4; j++)
                bf[j] = *(const bf16x8*)&b_s[(wn + j*16 + l16)*64 + ks*32 + qd*8];
            #pragma unroll
            for (int i = 0; i < 4; i++) {
                #pragma unroll
                for (int j = 0; j < 4; j++)
                    acc[i][j] = __builtin_amdgcn_mfma_f32_16x16x32_bf16(
                        af[i], bf[j], acc[i][j], 0, 0, 0);
            }
        }
        __syncthreads();
    }
    #pragma unroll
    for (int i = 0; i < 4; i++) {
        #pragma unroll
        for (int j = 0; j < 4; j++) {
            #pragma unroll
            for (int r = 0; r < 4; r++) {
                int row = r0 + wm + i*16 + qd*4 + r;
                int col = c0 + wn + j*16 + l16;
                C[(size_t)row*1024 + col] = f2bf(acc[i][j][r]);
            }
        }
    }
}

// ---- conv(4)+silu + x_proj MFMA + dt_proj + phase1 + (last-32-blocks ph2) ----
__global__ __launch_bounds__(512) void conv_xproj512(
    const ushort_t* __restrict__ xz, const float* __restrict__ cw,
    const float* __restrict__ cb, const ushort_t* __restrict__ XWb,
    const float* __restrict__ DTW, const float* __restrict__ DTB,
    const float* __restrict__ Alog,
    ushort_t* __restrict__ u_bf, float* __restrict__ bn,
    float* __restrict__ cn, ushort_t* __restrict__ dtn,
    float2* __restrict__ sa, float* __restrict__ sinc,
    unsigned int* __restrict__ cnt)
{
    __shared__ ushort_t xs[19][520];
    __shared__ ushort_t us[16][520];
    __shared__ float ps[8*768];
    __shared__ float dtr_s[16][16];
    __shared__ unsigned int tkt;
    const int c = blockIdx.x, b = blockIdx.y, l0 = c*CL_;
    const int tid = threadIdx.x;
    const int lane = tid & 63, w = tid >> 6;
    const int qd = lane >> 4, l16 = lane & 15;
    for (int f = tid; f < 19*64; f += 512) {
        int row = f >> 6, c8 = (f & 63)*8;
        int l = l0 - 3 + row;
        uint4 v = {0u,0u,0u,0u};
        if (l >= 0) v = *(const uint4*)(xz + (size_t)(b*L_ + l)*1024 + c8);
        *(uint4*)&xs[row][c8] = v;
    }
    __syncthreads();
    {
        int ch = tid;                           // one channel per thread
        float4 wv = *(const float4*)(cw + ch*4);
        float bias = cb[ch];
        float x0 = bf2f(xs[0][ch]);
        float x1 = bf2f(xs[1][ch]);
        float x2 = bf2f(xs[2][ch]);
        #pragma unroll
        for (int j = 0; j < 16; j++) {
            float x3 = bf2f(xs[3 + j][ch]);
            float v = fmaf(x0, wv.x, fmaf(x1, wv.y, fmaf(x2, wv.z, fmaf(x3, wv.w, bias))));
            us[j][ch] = f2bf(siluf(v));
            x0 = x1; x1 = x2; x2 = x3;
        }
    }
    __syncthreads();
    for (int f = tid; f < 16*64; f += 512) {
        int row = f >> 6, c8 = (f & 63)*8;
        *(uint4*)(u_bf + (size_t)(b*L_ + l0 + row)*512 + c8) =
            *(const uint4*)&us[row][c8];
    }
    f32x4 acc[3] = {};
    #pragma unroll
    for (int st = 0; st < 2; st++) {
        int k = w*64 + st*32 + qd*8;
        bf16x8 af = *(const bf16x8*)&us[l16][k];
        #pragma unroll
        for (int j = 0; j < 3; j++) {
            bf16x8 bv = *(const bf16x8*)(XWb + (size_t)(j*16 + l16)*512 + k);
            acc[j] = __builtin_amdgcn_mfma_f32_16x16x32_bf16(af, bv, acc[j], 0, 0, 0);
        }
    }
    #pragma unroll
    for (int j = 0; j < 3; j++)
        #pragma unroll
        for (int r = 0; r < 4; r++)
            ps[w*768 + (qd*4 + r)*48 + j*16 + l16] = acc[j][r];
    __syncthreads();
    for (int e = tid; e < 768; e += 512) {
        float v = ps[e] + ps[768+e] + ps[1536+e] + ps[2304+e]
                + ps[3072+e] + ps[3840+e] + ps[4608+e] + ps[5376+e];
        ps[e] = v;
    }
    __syncthreads();
    if (tid < 256) {
        int row = tid >> 4, n = tid & 15;
        dtr_s[row][n] = ps[row*48 + n];
        size_t base = ((size_t)(b*L_) + l0 + row)*DS_ + n;
        bn[base] = ps[row*48 + 16 + n];
        cn[base] = ps[row*48 + 32 + n];
    }
    __syncthreads();
    {
        const int d = tid;
        float wreg[16];
        const float4* wp = (const float4*)(DTW + (size_t)d*16);
        #pragma unroll
        for (int k4 = 0; k4 < 4; k4++) {
            float4 v = wp[k4];
            wreg[4*k4+0] = v.x; wreg[4*k4+1] = v.y;
            wreg[4*k4+2] = v.z; wreg[4*k4+3] = v.w;
        }
        float bias = DTB[d];
        float dtv[16];
        #pragma unroll
        for (int r = 0; r < 16; r++) {
            float a = bias;
            #pragma unroll
            for (int k = 0; k < 16; k++) a = fmaf(dtr_s[r][k], wreg[k], a);
            float dt = a > 20.f ? a : log1pf(__expf(a));
            ushort_t dtb16 = f2bf(dt);
            dtn[((size_t)(b*L_) + l0 + r)*DI_ + d] = dtb16;
            dtv[r] = bf2f(dtb16);
        }
        float Ac[DS_], s[DS_], ap[DS_];
        const float* ar = Alog + (size_t)d*DS_;
        #pragma unroll
        for (int n = 0; n < DS_; n++) { Ac[n] = -__expf(ar[n]); s[n] = 0.f; ap[n] = 1.f; }
        #pragma unroll
        for (int l = 0; l < 16; l++) {
            float dt = dtv[l];
            float u  = bf2f(us[l][d]);
            float dtu = dt*u;
            #pragma unroll
            for (int n = 0; n < DS_; n++) {
                float e = __expf(dt*Ac[n]);
                s[n] = fmaf(e, s[n], dtu*ps[l*48 + 16 + n]);
                ap[n] *= e;
            }
        }
        size_t ib = (((size_t)c*B_ + b)*DI_ + d)*DS_;
        float2* sap = sa + ib;
        #pragma unroll
        for (int k = 0; k < 8; k++)
            *(float4*)&sap[2*k] = make_float4(s[2*k], ap[2*k], s[2*k+1], ap[2*k+1]);
    }
    // ---- ticket: last NPH2B_ finishers run ph2 in-kernel ----
    // drain all waves' sa stores, then barrier, then RELEASE increment
    // (release forces XCD-L2 writeback of the sa lines to the LLC).
    asm volatile("s_waitcnt vmcnt(0)" ::: "memory");
    __syncthreads();
    if (tid == 0)
        tkt = __hip_atomic_fetch_add(cnt, 1u, __ATOMIC_RELEASE,
                                     __HIP_MEMORY_SCOPE_AGENT);
    __syncthreads();
    const unsigned int ticket = tkt;
    if (ticket < NCONVB_ - NPH2B_) return;
    // ACQUIRE poll (R5-verified): each poll invalidates local caches so the
    // final count and the released sa data cannot be served stale.
    if (tid == 0) {
        while (__hip_atomic_load(cnt, __ATOMIC_ACQUIRE,
                                 __HIP_MEMORY_SCOPE_AGENT) < (unsigned int)NCONVB_)
            __builtin_amdgcn_s_sleep(16);
    }
    __syncthreads();
    {
        const int t = (int)(ticket - (NCONVB_ - NPH2B_))*512 + tid;  // 0..16383
        const unsigned long long* sap = (const unsigned long long*)sa;
        float s = 0.f;
        for (int g = 0; g < 5; g++) {
            float2 v[25];
            #pragma unroll
            for (int i = 0; i < 25; i++)
                v[i] = __builtin_bit_cast(float2,
                    __hip_atomic_load(&sap[(size_t)(g*25 + i)*NST_ + t],
                                      __ATOMIC_RELAXED, __HIP_MEMORY_SCOPE_AGENT));
            #pragma unroll
            for (int i = 0; i < 25; i++) {
                sinc[(size_t)(g*25 + i)*NST_ + t] = s;
                s = fmaf(v[i].y, s, v[i].x);
            }
        }
    }
}

// ---- fused phase3 + out_proj + residual + LN + (next in_proj | head) ----
template<int LAST>
__global__ __launch_bounds__(512) void phase3_fused(
    const ushort_t* __restrict__ dtn, const ushort_t* __restrict__ u_bf,
    const float* __restrict__ bn, const float* __restrict__ cn,
    const float* __restrict__ Alog, const float* __restrict__ Dv,
    const float* __restrict__ sinc, const ushort_t* __restrict__ xz,
    const ushort_t* __restrict__ opw, float* __restrict__ h,
    const float* __restrict__ lnw, const float* __restrict__ lnb,
    const ushort_t* __restrict__ ipw, ushort_t* __restrict__ xz_out,
    const float* __restrict__ hw, const float* __restrict__ hb,
    float* __restrict__ out)
{
    __shared__ float b_sh[CL_*DS_];
    __shared__ float c_sh[CL_*DS_];
    __shared__ ushort_t ys[16][520];
    __shared__ union { ushort_t dt_t[16][520]; ushort_t z_t[16][520]; } T0;
    __shared__ union { ushort_t u_t[16][520];  ushort_t a_sh[16][264]; } T1;
    __shared__ float2 red2[128];
    __shared__ float2 muv[16];
    const int c = blockIdx.x, b = blockIdx.y, l0 = c*CL_;
    const int tid = threadIdx.x;
    const int w = tid >> 6, lane = tid & 63;
    const int qd = lane >> 4, l16 = lane & 15;
    {
        int f = tid & 255;
        size_t src = ((size_t)(b*L_) + l0)*DS_ + f;
        if (tid < 256) b_sh[f] = bn[src];
        else           c_sh[f] = cn[src];
    }
    {
        const int r = tid >> 5, cb16 = (tid & 31)*16;
        size_t rb = ((size_t)(b*L_) + l0 + r)*DI_ + cb16;
        *(uint4*)&T0.dt_t[r][cb16]     = *(const uint4*)(dtn + rb);
        *(uint4*)&T0.dt_t[r][cb16 + 8] = *(const uint4*)(dtn + rb + 8);
        *(uint4*)&T1.u_t[r][cb16]      = *(const uint4*)(u_bf + rb);
        *(uint4*)&T1.u_t[r][cb16 + 8]  = *(const uint4*)(u_bf + rb + 8);
    }
    const int d = tid;
    float Ac[DS_], s[DS_];
    {
        const float* ar = Alog + (size_t)d*DS_;
        #pragma unroll
        for (int n = 0; n < DS_; n++) Ac[n] = -__expf(ar[n]);
        size_t base = (((size_t)c*B_ + b)*DI_ + d)*DS_;
        #pragma unroll
        for (int n4 = 0; n4 < 4; n4++)
            *(float4*)&s[4*n4] = *(const float4*)(sinc + base + 4*n4);
    }
    const float Dd = Dv[d];
    __syncthreads();
    float y_reg[CL_];
    #pragma unroll
    for (int l = 0; l < CL_; l++) {
        float dt = bf2f(T0.dt_t[l][d]);
        float u  = bf2f(T1.u_t[l][d]);
        float dtu = dt*u;
        float y = u*Dd;
        #pragma unroll
        for (int n = 0; n < DS_; n++) {
            float e = __expf(dt*Ac[n]);
            s[n] = fmaf(e, s[n], dtu*b_sh[l*DS_ + n]);
            y = fmaf(s[n], c_sh[l*DS_ + n], y);
        }
        y_reg[l] = y;
    }
    __syncthreads();
    {
        const int r = tid >> 5, cb16 = (tid & 31)*16;
        size_t rb = ((size_t)(b*L_) + l0 + r)*1024 + 512 + cb16;
        *(uint4*)&T0.z_t[r][cb16]     = *(const uint4*)(xz + rb);
        *(uint4*)&T0.z_t[r][cb16 + 8] = *(const uint4*)(xz + rb + 8);
    }
    __syncthreads();
    #pragma unroll
    for (int l = 0; l < CL_; l++)
        ys[l][d] = f2bf(y_reg[l] * siluf(bf2f(T0.z_t[l][d])));
    __syncthreads();
    f32x4 acc[2] = {};
    #pragma unroll
    for (int ks = 0; ks < 16; ks++) {
        bf16x8 af = *(const bf16x8*)&ys[l16][ks*32 + qd*8];
        #pragma unroll
        for (int j = 0; j < 2; j++) {
            bf16x8 bv = *(const bf16x8*)(opw + (size_t)(w*32 + j*16 + l16)*DI_ + ks*32 + qd*8);
            acc[j] = __builtin_amdgcn_mfma_f32_16x16x32_bf16(af, bv, acc[j], 0, 0, 0);
        }
    }
    float v[2][4];
    #pragma unroll
    for (int r = 0; r < 4; r++) {
        int lrow = qd*4 + r;
        size_t gr = (size_t)(b*L_ + l0 + lrow);
        float sm = 0.f, sq = 0.f;
        #pragma unroll
        for (int j = 0; j < 2; j++) {
            int col = w*32 + j*16 + l16;
            size_t idx = gr*DM_ + col;
            float vv = h[idx] + acc[j][r];
            if (!LAST) h[idx] = vv;
            v[j][r] = vv;
            sm += vv; sq += vv*vv;
        }
        sm += __shfl_xor(sm, 1); sq += __shfl_xor(sq, 1);
        sm += __shfl_xor(sm, 2); sq += __shfl_xor(sq, 2);
        sm += __shfl_xor(sm, 4); sq += __shfl_xor(sq, 4);
        sm += __shfl_xor(sm, 8); sq += __shfl_xor(sq, 8);
        if (l16 == 0) red2[w*16 + lrow] = make_float2(sm, sq);
    }
    __syncthreads();
    if (tid < 16) {
        float sm = 0.f, sq = 0.f;
        #pragma unroll
        for (int ww = 0; ww < 8; ww++) {
            float2 t = red2[ww*16 + tid];
            sm += t.x; sq += t.y;
        }
        float mu  = sm*(1.f/DM_);
        float inv = rsqrtf(fmaxf(sq*(1.f/DM_) - mu*mu, 0.f) + 1e-5f);
        muv[tid] = make_float2(mu, inv);
    }
    __syncthreads();
    if (!LAST) {
        #pragma unroll
        for (int r = 0; r < 4; r++) {
            int lrow = qd*4 + r;
            float2 mi = muv[lrow];
            #pragma unroll
            for (int j = 0; j < 2; j++) {
                int col = w*32 + j*16 + l16;
                T1.a_sh[lrow][col] = f2bf((v[j][r] - mi.x)*mi.y*lnw[col] + lnb[col]);
            }
        }
        __syncthreads();
        f32x4 acc2[8] = {};
        const int n0 = w*128;
        #pragma unroll
        for (int ks = 0; ks < 8; ks++) {
            bf16x8 af = *(const bf16x8*)&T1.a_sh[l16][ks*32 + qd*8];
            #pragma unroll
            for (int j2 = 0; j2 < 8; j2++) {
                bf16x8 bv = *(const bf16x8*)(ipw + (size_t)(n0 + j2*16 + l16)*DM_ + ks*32 + qd*8);
                acc2[j2] = __builtin_amdgcn_mfma_f32_16x16x32_bf16(af, bv, acc2[j2], 0, 0, 0);
            }
        }
        #pragma unroll
        for (int j2 = 0; j2 < 8; j2++) {
            #pragma unroll
            for (int r = 0; r < 4; r++) {
                size_t row = (size_t)(b*L_ + l0 + qd*4 + r);
                xz_out[row*1024 + n0 + j2*16 + l16] = f2bf(acc2[j2][r]);
            }
        }
    } else {
        float hd[4];
        #pragma unroll
        for (int r = 0; r < 4; r++) {
            int lrow = qd*4 + r;
            float2 mi = muv[lrow];
            float aa = 0.f;
            #pragma unroll
            for (int j = 0; j < 2; j++) {
                int col = w*32 + j*16 + l16;
                float nv = (v[j][r] - mi.x)*mi.y*lnw[col] + lnb[col];
                aa = fmaf(nv, hw[col], aa);
            }
            hd[r] = aa;
        }
        #pragma unroll
        for (int r = 0; r < 4; r++) {
            float xv = hd[r];
            xv += __shfl_xor(xv, 1); xv += __shfl_xor(xv, 2);
            xv += __shfl_xor(xv, 4); xv += __shfl_xor(xv, 8);
            if (l16 == 0) red2[w*16 + qd*4 + r].x = xv;
        }
        __syncthreads();
        if (tid < 16) {
            float xv = 0.f;
            #pragma unroll
            for (int ww = 0; ww < 8; ww++) xv += red2[ww*16 + tid].x;
            out[(size_t)(b*L_) + l0 + tid] = xv + hb[0];
        }
    }
}

extern "C" void kernel_launch(void* const* d_in, const int* in_sizes, int n_in,
                              void* d_out, int out_size, void* d_ws, size_t ws_size,
                              hipStream_t stream)
{
    const float* x    = (const float*)d_in[0];
    const float* biw  = (const float*)d_in[1];
    const float* bib  = (const float*)d_in[2];
    const float* ge   = (const float*)d_in[3];
    const float* me   = (const float*)d_in[4];
    const float* lnw  = (const float*)d_in[5];
    const float* lnb  = (const float*)d_in[6];
    const float* ipw  = (const float*)d_in[7];
    const float* cw   = (const float*)d_in[8];
    const float* cb   = (const float*)d_in[9];
    const float* xpw  = (const float*)d_in[10];
    const float* dtw  = (const float*)d_in[11];
    const float* dtb  = (const float*)d_in[12];
    const float* alog = (const float*)d_in[13];
    const float* Dv   = (const float*)d_in[14];
    const float* opw  = (const float*)d_in[15];
    const float* fw   = (const float*)d_in[16];
    const float* fb   = (const float*)d_in[17];
    const float* hw   = (const float*)d_in[18];
    const float* hb   = (const float*)d_in[19];
    float* out = (float*)d_out;

    // workspace layout (16B-aligned segments); ~50 MB
    float* ws  = (float*)d_ws;
    float* h      = ws;                                   // BLP_*DM_ f
    float* bn     = h + (size_t)BLP_*DM_;                 // B_*L_*DS_ f
    float* cn     = bn + (size_t)B_*L_*DS_;               // B_*L_*DS_ f
    float2* sa    = (float2*)(cn + (size_t)B_*L_*DS_);    // NC_*NST_ float2
    float* sinc   = (float*)(sa + (size_t)NC_*NST_);      // NC_*NST_ f
    ushort_t* aln   = (ushort_t*)(sinc + (size_t)NC_*NST_); // BLP_*DM_ us
    ushort_t* xz_bf = aln + (size_t)BLP_*DM_;             // BLP_*1024 us
    ushort_t* u_bf  = xz_bf + (size_t)BLP_*1024;          // BLP_*DI_ us
    ushort_t* dtn   = u_bf + (size_t)BLP_*DI_;            // B_*L_*DI_ us
    ushort_t* ipwb  = dtn + (size_t)B_*L_*DI_;            // NL_*1024*DM_ us
    ushort_t* opwb  = ipwb + (size_t)NL_*1024*DM_;        // NL_*DM_*DI_ us
    ushort_t* xpwb  = opwb + (size_t)NL_*DM_*DI_;         // NL_*48*512 us
    unsigned int* cnt = (unsigned int*)(xpwb + (size_t)NL_*48*512);  // NL_ u32

    const int N0 = NL_*1024*DM_/4, N1 = NL_*DM_*DI_/4, N2 = NL_*48*512/4;
    const int conv_blocks = (N0+N1+N2 + 255)/256;
    embed_f2bf_kernel<<<BL_ + conv_blocks, 256, 0, stream>>>(
        x, biw, bib, ge, me, lnw, lnb, h, aln,
        ipw, opw, xpw, ipwb, opwb, xpwb, N0, N1, N2, cnt);

    gemm_bf<<<dim3(BLP_/128, 1024/128), 256, 0, stream>>>(
        aln, ipwb, xz_bf);

    for (int i = 0; i < NL_; i++) {
        conv_xproj512<<<dim3(NC_, B_), 512, 0, stream>>>(
            xz_bf, cw + i*DI_*4, cb + i*DI_, xpwb + (size_t)i*48*512,
            dtw + (size_t)i*DI_*16, dtb + i*DI_, alog + (size_t)i*DI_*DS_,
            u_bf, bn, cn, dtn, sa, sinc, cnt + i);
        if (i < NL_-1) {
            phase3_fused<0><<<dim3(NC_, B_), 512, 0, stream>>>(
                dtn, u_bf, bn, cn, alog + (size_t)i*DI_*DS_, Dv + i*DI_,
                sinc, xz_bf, opwb + (size_t)i*DM_*DI_, h,
                lnw + (i+1)*DM_, lnb + (i+1)*DM_,
                ipwb + (size_t)(i+1)*1024*DM_, xz_bf,
                nullptr, nullptr, nullptr);
        } else {
            phase3_fused<1><<<dim3(NC_, B_), 512, 0, stream>>>(
                dtn, u_bf, bn, cn, alog + (size_t)i*DI_*DS_, Dv + i*DI_,
                sinc, xz_bf, opwb + (size_t)i*DM_*DI_, h,
                fw, fb,
                nullptr, xz_bf,
                hw, hb, out);
        }
    }
}

// Round 10
// 400.659 us; speedup vs baseline: 1.2691x; 1.2691x over previous
//
#include <hip/hip_runtime.h>
#include <math.h>

#define B_  2
#define L_  2000
#define DM_ 256
#define DI_ 512
#define DS_ 16
#define NL_ 4
#define BL_ (B_*L_)     // 4000
#define BLP_ 4096       // rows padded to multiple of 64
#define NC_  125        // scan chunks == conv strips (CL=16)
#define CL_  16
#define NST_ (B_*DI_*DS_)   // 16384 scan states

typedef unsigned short ushort_t;
typedef __attribute__((ext_vector_type(8))) short bf16x8;
typedef __attribute__((ext_vector_type(4))) float f32x4;

__device__ __forceinline__ float siluf(float x) { return x / (1.f + __expf(-x)); }
__device__ __forceinline__ ushort_t f2bf(float x) {
    unsigned int u = __float_as_uint(x);
    return (ushort_t)((u + 0x7FFFu + ((u >> 16) & 1u)) >> 16);
}
__device__ __forceinline__ float bf2f(ushort_t v) {
    return __uint_as_float(((unsigned int)v) << 16);
}

// ---- merged embed + layer-0 LN (blocks 0..BL_-1) + weight f2bf (rest) ----
// Emits h (f32 residual stream) and aln (bf16 LN'd row, layer-0 lnw/lnb).
__global__ __launch_bounds__(256) void embed_f2bf_kernel(
    const float* __restrict__ x, const float* __restrict__ biw,
    const float* __restrict__ bib, const float* __restrict__ ge,
    const float* __restrict__ me, const float* __restrict__ lnw,
    const float* __restrict__ lnb,
    float* __restrict__ h, ushort_t* __restrict__ aln,
    const float* __restrict__ s0, const float* __restrict__ s1,
    const float* __restrict__ s2, ushort_t* __restrict__ d0,
    ushort_t* __restrict__ d1, ushort_t* __restrict__ d2,
    int N0, int N1, int N2)
{
    if (blockIdx.x < BL_) {
        __shared__ float sm[8];
        int bl = blockIdx.x, d = threadIdx.x;
        int l = bl % L_;
        float v = x[bl]*biw[d] + bib[d] + ge[(size_t)l*DM_ + d] + me[d];
        h[(size_t)bl*DM_ + d] = v;
        float s = v, q = v*v;
        #pragma unroll
        for (int o = 32; o > 0; o >>= 1) {
            s += __shfl_down(s, o);
            q += __shfl_down(q, o);
        }
        if ((d & 63) == 0) { sm[d >> 6] = s; sm[4 + (d >> 6)] = q; }
        __syncthreads();
        float sum = sm[0]+sm[1]+sm[2]+sm[3];
        float ssq = sm[4]+sm[5]+sm[6]+sm[7];
        float mu  = sum * (1.f/DM_);
        float inv = rsqrtf(fmaxf(ssq*(1.f/DM_) - mu*mu, 0.f) + 1e-5f);
        aln[(size_t)bl*DM_ + d] = f2bf((v - mu)*inv*lnw[d] + lnb[d]);
    } else {
        int i = (blockIdx.x - BL_)*256 + threadIdx.x;
        const float* s; ushort_t* d; int j;
        if (i < N0)           { s = s0; d = d0; j = i; }
        else if (i < N0+N1)   { s = s1; d = d1; j = i - N0; }
        else if (i < N0+N1+N2){ s = s2; d = d2; j = i - N0 - N1; }
        else return;
        float4 v = *(const float4*)(s + 4*j);
        ushort_t o[4] = {f2bf(v.x), f2bf(v.y), f2bf(v.z), f2bf(v.w)};
        *(ushort2*)(d + 4*j)     = *(ushort2*)&o[0];
        *(ushort2*)(d + 4*j + 2) = *(ushort2*)&o[2];
    }
}

// ---- layer 0: fused in_proj (from aln) + conv + x_proj + dt_proj + phase1 ----
// Each block computes its own 19 rows of the in_proj u-half (rows l0-3..l0+15,
// pad to 32 for MFMA) directly into LDS, plus the z-half of its 16 owned rows
// to global. Removes the standalone layer-0 GEMM kernel + boundary.
__global__ __launch_bounds__(512) void conv0_inproj(
    const ushort_t* __restrict__ aln, const ushort_t* __restrict__ IPW,
    ushort_t* __restrict__ xz,
    const float* __restrict__ cw, const float* __restrict__ cb,
    const ushort_t* __restrict__ XWb,
    const float* __restrict__ DTW, const float* __restrict__ DTB,
    const float* __restrict__ Alog,
    ushort_t* __restrict__ u_bf, float* __restrict__ bn,
    float* __restrict__ cn, ushort_t* __restrict__ dtn,
    float2* __restrict__ sa)
{
    __shared__ ushort_t xs[19][520];
    __shared__ ushort_t us[16][520];
    __shared__ union { float ps[8*768]; ushort_t als[32][264]; } U;
    __shared__ float dtr_s[16][16];
    const int c = blockIdx.x, b = blockIdx.y, l0 = c*CL_;
    const int tid = threadIdx.x;
    const int lane = tid & 63, w = tid >> 6;
    const int qd = lane >> 4, l16 = lane & 15;
    // --- phase A: stage aln rows l0-3..l0+15 (pad to 32 rows) ---
    {
        int row = tid >> 4, c16 = (tid & 15)*16;
        int gl = l0 - 3 + row;
        uint4 v0 = {0u,0u,0u,0u}, v1 = {0u,0u,0u,0u};
        if (row < 19 && gl >= 0) {
            const ushort_t* p = aln + ((size_t)(b*L_ + gl))*DM_ + c16;
            v0 = *(const uint4*)p;
            v1 = *(const uint4*)(p + 8);
        }
        *(uint4*)&U.als[row][c16]     = v0;
        *(uint4*)&U.als[row][c16 + 8] = v1;
    }
    __syncthreads();
    // --- phase B: in_proj MFMA; wave w covers cols n0..n0+127 ---
    const int n0 = w*128;
    f32x4 accI[2][8] = {};
    #pragma unroll
    for (int ks = 0; ks < 8; ks++) {
        bf16x8 af0 = *(const bf16x8*)&U.als[l16][ks*32 + qd*8];
        bf16x8 af1 = *(const bf16x8*)&U.als[16 + l16][ks*32 + qd*8];
        #pragma unroll
        for (int j2 = 0; j2 < 8; j2++) {
            bf16x8 bv = *(const bf16x8*)(IPW + (size_t)(n0 + j2*16 + l16)*DM_ + ks*32 + qd*8);
            accI[0][j2] = __builtin_amdgcn_mfma_f32_16x16x32_bf16(af0, bv, accI[0][j2], 0, 0, 0);
            accI[1][j2] = __builtin_amdgcn_mfma_f32_16x16x32_bf16(af1, bv, accI[1][j2], 0, 0, 0);
        }
    }
    // --- phase C: scatter u-half -> xs (LDS), z-half (own 16 rows) -> global ---
    #pragma unroll
    for (int m = 0; m < 2; m++) {
        #pragma unroll
        for (int j2 = 0; j2 < 8; j2++) {
            #pragma unroll
            for (int r = 0; r < 4; r++) {
                int row_l = m*16 + qd*4 + r;
                int col = n0 + j2*16 + l16;
                ushort_t val = f2bf(accI[m][j2][r]);
                if (col < 512) {
                    if (row_l < 19) xs[row_l][col] = val;
                } else if (row_l >= 3 && row_l < 19) {
                    xz[((size_t)(b*L_ + l0 + row_l - 3))*1024 + col] = val;
                }
            }
        }
    }
    __syncthreads();
    // --- conv(4)+silu -> us ---
    {
        int ch = tid;
        float4 wv = *(const float4*)(cw + ch*4);
        float bias = cb[ch];
        float x0 = bf2f(xs[0][ch]);
        float x1 = bf2f(xs[1][ch]);
        float x2 = bf2f(xs[2][ch]);
        #pragma unroll
        for (int j = 0; j < 16; j++) {
            float x3 = bf2f(xs[3 + j][ch]);
            float v = fmaf(x0, wv.x, fmaf(x1, wv.y, fmaf(x2, wv.z, fmaf(x3, wv.w, bias))));
            us[j][ch] = f2bf(siluf(v));
            x0 = x1; x1 = x2; x2 = x3;
        }
    }
    __syncthreads();
    for (int f = tid; f < 16*64; f += 512) {
        int row = f >> 6, c8 = (f & 63)*8;
        *(uint4*)(u_bf + (size_t)(b*L_ + l0 + row)*512 + c8) =
            *(const uint4*)&us[row][c8];
    }
    // --- x_proj MFMA ---
    f32x4 acc[3] = {};
    #pragma unroll
    for (int st = 0; st < 2; st++) {
        int k = w*64 + st*32 + qd*8;
        bf16x8 af = *(const bf16x8*)&us[l16][k];
        #pragma unroll
        for (int j = 0; j < 3; j++) {
            bf16x8 bv = *(const bf16x8*)(XWb + (size_t)(j*16 + l16)*512 + k);
            acc[j] = __builtin_amdgcn_mfma_f32_16x16x32_bf16(af, bv, acc[j], 0, 0, 0);
        }
    }
    #pragma unroll
    for (int j = 0; j < 3; j++)
        #pragma unroll
        for (int r = 0; r < 4; r++)
            U.ps[w*768 + (qd*4 + r)*48 + j*16 + l16] = acc[j][r];
    __syncthreads();
    for (int e = tid; e < 768; e += 512) {
        float v = U.ps[e] + U.ps[768+e] + U.ps[1536+e] + U.ps[2304+e]
                + U.ps[3072+e] + U.ps[3840+e] + U.ps[4608+e] + U.ps[5376+e];
        U.ps[e] = v;
    }
    __syncthreads();
    if (tid < 256) {
        int row = tid >> 4, n = tid & 15;
        dtr_s[row][n] = U.ps[row*48 + n];
        size_t base = ((size_t)(b*L_) + l0 + row)*DS_ + n;
        bn[base] = U.ps[row*48 + 16 + n];
        cn[base] = U.ps[row*48 + 32 + n];
    }
    __syncthreads();
    // --- dt_proj + phase1 ---
    {
        const int d = tid;
        float wreg[16];
        const float4* wp = (const float4*)(DTW + (size_t)d*16);
        #pragma unroll
        for (int k4 = 0; k4 < 4; k4++) {
            float4 v = wp[k4];
            wreg[4*k4+0] = v.x; wreg[4*k4+1] = v.y;
            wreg[4*k4+2] = v.z; wreg[4*k4+3] = v.w;
        }
        float bias = DTB[d];
        float dtv[16];
        #pragma unroll
        for (int r = 0; r < 16; r++) {
            float a = bias;
            #pragma unroll
            for (int k = 0; k < 16; k++) a = fmaf(dtr_s[r][k], wreg[k], a);
            float dt = a > 20.f ? a : log1pf(__expf(a));
            ushort_t dtb16 = f2bf(dt);
            dtn[((size_t)(b*L_) + l0 + r)*DI_ + d] = dtb16;
            dtv[r] = bf2f(dtb16);
        }
        float Ac[DS_], s[DS_], ap[DS_];
        const float* ar = Alog + (size_t)d*DS_;
        #pragma unroll
        for (int n = 0; n < DS_; n++) { Ac[n] = -__expf(ar[n]); s[n] = 0.f; ap[n] = 1.f; }
        #pragma unroll
        for (int l = 0; l < 16; l++) {
            float dt = dtv[l];
            float u  = bf2f(us[l][d]);
            float dtu = dt*u;
            #pragma unroll
            for (int n = 0; n < DS_; n++) {
                float e = __expf(dt*Ac[n]);
                s[n] = fmaf(e, s[n], dtu*U.ps[l*48 + 16 + n]);
                ap[n] *= e;
            }
        }
        size_t ib = (((size_t)c*B_ + b)*DI_ + d)*DS_;
        float2* sap = sa + ib;
        #pragma unroll
        for (int k = 0; k < 8; k++)
            *(float4*)&sap[2*k] = make_float4(s[2*k], ap[2*k], s[2*k+1], ap[2*k+1]);
    }
}

// ---- conv(4)+silu + x_proj MFMA + dt_proj + scan phase1 : layers 1..3 ----
__global__ __launch_bounds__(512) void conv_xproj512(
    const ushort_t* __restrict__ xz, const float* __restrict__ cw,
    const float* __restrict__ cb, const ushort_t* __restrict__ XWb,
    const float* __restrict__ DTW, const float* __restrict__ DTB,
    const float* __restrict__ Alog,
    ushort_t* __restrict__ u_bf, float* __restrict__ bn,
    float* __restrict__ cn, ushort_t* __restrict__ dtn,
    float2* __restrict__ sa)
{
    __shared__ ushort_t xs[19][520];
    __shared__ ushort_t us[16][520];
    __shared__ float ps[8*768];
    __shared__ float dtr_s[16][16];
    const int c = blockIdx.x, b = blockIdx.y, l0 = c*CL_;
    const int tid = threadIdx.x;
    const int lane = tid & 63, w = tid >> 6;
    const int qd = lane >> 4, l16 = lane & 15;
    for (int f = tid; f < 19*64; f += 512) {
        int row = f >> 6, c8 = (f & 63)*8;
        int l = l0 - 3 + row;
        uint4 v = {0u,0u,0u,0u};
        if (l >= 0) v = *(const uint4*)(xz + (size_t)(b*L_ + l)*1024 + c8);
        *(uint4*)&xs[row][c8] = v;
    }
    __syncthreads();
    {
        int ch = tid;
        float4 wv = *(const float4*)(cw + ch*4);
        float bias = cb[ch];
        float x0 = bf2f(xs[0][ch]);
        float x1 = bf2f(xs[1][ch]);
        float x2 = bf2f(xs[2][ch]);
        #pragma unroll
        for (int j = 0; j < 16; j++) {
            float x3 = bf2f(xs[3 + j][ch]);
            float v = fmaf(x0, wv.x, fmaf(x1, wv.y, fmaf(x2, wv.z, fmaf(x3, wv.w, bias))));
            us[j][ch] = f2bf(siluf(v));
            x0 = x1; x1 = x2; x2 = x3;
        }
    }
    __syncthreads();
    for (int f = tid; f < 16*64; f += 512) {
        int row = f >> 6, c8 = (f & 63)*8;
        *(uint4*)(u_bf + (size_t)(b*L_ + l0 + row)*512 + c8) =
            *(const uint4*)&us[row][c8];
    }
    f32x4 acc[3] = {};
    #pragma unroll
    for (int st = 0; st < 2; st++) {
        int k = w*64 + st*32 + qd*8;
        bf16x8 af = *(const bf16x8*)&us[l16][k];
        #pragma unroll
        for (int j = 0; j < 3; j++) {
            bf16x8 bv = *(const bf16x8*)(XWb + (size_t)(j*16 + l16)*512 + k);
            acc[j] = __builtin_amdgcn_mfma_f32_16x16x32_bf16(af, bv, acc[j], 0, 0, 0);
        }
    }
    #pragma unroll
    for (int j = 0; j < 3; j++)
        #pragma unroll
        for (int r = 0; r < 4; r++)
            ps[w*768 + (qd*4 + r)*48 + j*16 + l16] = acc[j][r];
    __syncthreads();
    for (int e = tid; e < 768; e += 512) {
        float v = ps[e] + ps[768+e] + ps[1536+e] + ps[2304+e]
                + ps[3072+e] + ps[3840+e] + ps[4608+e] + ps[5376+e];
        ps[e] = v;
    }
    __syncthreads();
    if (tid < 256) {
        int row = tid >> 4, n = tid & 15;
        dtr_s[row][n] = ps[row*48 + n];
        size_t base = ((size_t)(b*L_) + l0 + row)*DS_ + n;
        bn[base] = ps[row*48 + 16 + n];
        cn[base] = ps[row*48 + 32 + n];
    }
    __syncthreads();
    {
        const int d = tid;
        float wreg[16];
        const float4* wp = (const float4*)(DTW + (size_t)d*16);
        #pragma unroll
        for (int k4 = 0; k4 < 4; k4++) {
            float4 v = wp[k4];
            wreg[4*k4+0] = v.x; wreg[4*k4+1] = v.y;
            wreg[4*k4+2] = v.z; wreg[4*k4+3] = v.w;
        }
        float bias = DTB[d];
        float dtv[16];
        #pragma unroll
        for (int r = 0; r < 16; r++) {
            float a = bias;
            #pragma unroll
            for (int k = 0; k < 16; k++) a = fmaf(dtr_s[r][k], wreg[k], a);
            float dt = a > 20.f ? a : log1pf(__expf(a));
            ushort_t dtb16 = f2bf(dt);
            dtn[((size_t)(b*L_) + l0 + r)*DI_ + d] = dtb16;
            dtv[r] = bf2f(dtb16);
        }
        float Ac[DS_], s[DS_], ap[DS_];
        const float* ar = Alog + (size_t)d*DS_;
        #pragma unroll
        for (int n = 0; n < DS_; n++) { Ac[n] = -__expf(ar[n]); s[n] = 0.f; ap[n] = 1.f; }
        #pragma unroll
        for (int l = 0; l < 16; l++) {
            float dt = dtv[l];
            float u  = bf2f(us[l][d]);
            float dtu = dt*u;
            #pragma unroll
            for (int n = 0; n < DS_; n++) {
                float e = __expf(dt*Ac[n]);
                s[n] = fmaf(e, s[n], dtu*ps[l*48 + 16 + n]);
                ap[n] *= e;
            }
        }
        size_t ib = (((size_t)c*B_ + b)*DI_ + d)*DS_;
        float2* sap = sa + ib;
        #pragma unroll
        for (int k = 0; k < 8; k++)
            *(float4*)&sap[2*k] = make_float4(s[2*k], ap[2*k], s[2*k+1], ap[2*k+1]);
    }
}

// ---- phase2: cross-chunk exclusive prefix ----
__global__ __launch_bounds__(64) void scan_phase2(
    const float2* __restrict__ sa, float* __restrict__ sinc)
{
    const int t = blockIdx.x*64 + threadIdx.x;
    float s = 0.f;
    for (int g = 0; g < 5; g++) {
        float2 v[25];
        #pragma unroll
        for (int i = 0; i < 25; i++)
            v[i] = sa[(size_t)(g*25 + i)*NST_ + t];
        #pragma unroll
        for (int i = 0; i < 25; i++) {
            sinc[(size_t)(g*25 + i)*NST_ + t] = s;
            s = fmaf(v[i].y, s, v[i].x);
        }
    }
}

// ---- fused phase3 + out_proj + residual + LN + (next in_proj | head) ----
template<int LAST>
__global__ __launch_bounds__(512) void phase3_fused(
    const ushort_t* __restrict__ dtn, const ushort_t* __restrict__ u_bf,
    const float* __restrict__ bn, const float* __restrict__ cn,
    const float* __restrict__ Alog, const float* __restrict__ Dv,
    const float* __restrict__ sinc, const ushort_t* __restrict__ xz,
    const ushort_t* __restrict__ opw, float* __restrict__ h,
    const float* __restrict__ lnw, const float* __restrict__ lnb,
    const ushort_t* __restrict__ ipw, ushort_t* __restrict__ xz_out,
    const float* __restrict__ hw, const float* __restrict__ hb,
    float* __restrict__ out)
{
    __shared__ float b_sh[CL_*DS_];
    __shared__ float c_sh[CL_*DS_];
    __shared__ ushort_t ys[16][520];
    __shared__ union { ushort_t dt_t[16][520]; ushort_t z_t[16][520]; } T0;
    __shared__ union { ushort_t u_t[16][520];  ushort_t a_sh[16][264]; } T1;
    __shared__ float2 red2[128];
    __shared__ float2 muv[16];
    const int c = blockIdx.x, b = blockIdx.y, l0 = c*CL_;
    const int tid = threadIdx.x;
    const int w = tid >> 6, lane = tid & 63;
    const int qd = lane >> 4, l16 = lane & 15;
    {
        int f = tid & 255;
        size_t src = ((size_t)(b*L_) + l0)*DS_ + f;
        if (tid < 256) b_sh[f] = bn[src];
        else           c_sh[f] = cn[src];
    }
    {
        const int r = tid >> 5, cb16 = (tid & 31)*16;
        size_t rb = ((size_t)(b*L_) + l0 + r)*DI_ + cb16;
        *(uint4*)&T0.dt_t[r][cb16]     = *(const uint4*)(dtn + rb);
        *(uint4*)&T0.dt_t[r][cb16 + 8] = *(const uint4*)(dtn + rb + 8);
        *(uint4*)&T1.u_t[r][cb16]      = *(const uint4*)(u_bf + rb);
        *(uint4*)&T1.u_t[r][cb16 + 8]  = *(const uint4*)(u_bf + rb + 8);
    }
    const int d = tid;
    float Ac[DS_], s[DS_];
    {
        const float* ar = Alog + (size_t)d*DS_;
        #pragma unroll
        for (int n = 0; n < DS_; n++) Ac[n] = -__expf(ar[n]);
        size_t base = (((size_t)c*B_ + b)*DI_ + d)*DS_;
        #pragma unroll
        for (int n4 = 0; n4 < 4; n4++)
            *(float4*)&s[4*n4] = *(const float4*)(sinc + base + 4*n4);
    }
    const float Dd = Dv[d];
    __syncthreads();
    float y_reg[CL_];
    #pragma unroll
    for (int l = 0; l < CL_; l++) {
        float dt = bf2f(T0.dt_t[l][d]);
        float u  = bf2f(T1.u_t[l][d]);
        float dtu = dt*u;
        float y = u*Dd;
        #pragma unroll
        for (int n = 0; n < DS_; n++) {
            float e = __expf(dt*Ac[n]);
            s[n] = fmaf(e, s[n], dtu*b_sh[l*DS_ + n]);
            y = fmaf(s[n], c_sh[l*DS_ + n], y);
        }
        y_reg[l] = y;
    }
    __syncthreads();
    {
        const int r = tid >> 5, cb16 = (tid & 31)*16;
        size_t rb = ((size_t)(b*L_) + l0 + r)*1024 + 512 + cb16;
        *(uint4*)&T0.z_t[r][cb16]     = *(const uint4*)(xz + rb);
        *(uint4*)&T0.z_t[r][cb16 + 8] = *(const uint4*)(xz + rb + 8);
    }
    __syncthreads();
    #pragma unroll
    for (int l = 0; l < CL_; l++)
        ys[l][d] = f2bf(y_reg[l] * siluf(bf2f(T0.z_t[l][d])));
    __syncthreads();
    f32x4 acc[2] = {};
    #pragma unroll
    for (int ks = 0; ks < 16; ks++) {
        bf16x8 af = *(const bf16x8*)&ys[l16][ks*32 + qd*8];
        #pragma unroll
        for (int j = 0; j < 2; j++) {
            bf16x8 bv = *(const bf16x8*)(opw + (size_t)(w*32 + j*16 + l16)*DI_ + ks*32 + qd*8);
            acc[j] = __builtin_amdgcn_mfma_f32_16x16x32_bf16(af, bv, acc[j], 0, 0, 0);
        }
    }
    float v[2][4];
    #pragma unroll
    for (int r = 0; r < 4; r++) {
        int lrow = qd*4 + r;
        size_t gr = (size_t)(b*L_ + l0 + lrow);
        float sm = 0.f, sq = 0.f;
        #pragma unroll
        for (int j = 0; j < 2; j++) {
            int col = w*32 + j*16 + l16;
            size_t idx = gr*DM_ + col;
            float vv = h[idx] + acc[j][r];
            if (!LAST) h[idx] = vv;
            v[j][r] = vv;
            sm += vv; sq += vv*vv;
        }
        sm += __shfl_xor(sm, 1); sq += __shfl_xor(sq, 1);
        sm += __shfl_xor(sm, 2); sq += __shfl_xor(sq, 2);
        sm += __shfl_xor(sm, 4); sq += __shfl_xor(sq, 4);
        sm += __shfl_xor(sm, 8); sq += __shfl_xor(sq, 8);
        if (l16 == 0) red2[w*16 + lrow] = make_float2(sm, sq);
    }
    __syncthreads();
    if (tid < 16) {
        float sm = 0.f, sq = 0.f;
        #pragma unroll
        for (int ww = 0; ww < 8; ww++) {
            float2 t = red2[ww*16 + tid];
            sm += t.x; sq += t.y;
        }
        float mu  = sm*(1.f/DM_);
        float inv = rsqrtf(fmaxf(sq*(1.f/DM_) - mu*mu, 0.f) + 1e-5f);
        muv[tid] = make_float2(mu, inv);
    }
    __syncthreads();
    if (!LAST) {
        #pragma unroll
        for (int r = 0; r < 4; r++) {
            int lrow = qd*4 + r;
            float2 mi = muv[lrow];
            #pragma unroll
            for (int j = 0; j < 2; j++) {
                int col = w*32 + j*16 + l16;
                T1.a_sh[lrow][col] = f2bf((v[j][r] - mi.x)*mi.y*lnw[col] + lnb[col]);
            }
        }
        __syncthreads();
        f32x4 acc2[8] = {};
        const int n0 = w*128;
        #pragma unroll
        for (int ks = 0; ks < 8; ks++) {
            bf16x8 af = *(const bf16x8*)&T1.a_sh[l16][ks*32 + qd*8];
            #pragma unroll
            for (int j2 = 0; j2 < 8; j2++) {
                bf16x8 bv = *(const bf16x8*)(ipw + (size_t)(n0 + j2*16 + l16)*DM_ + ks*32 + qd*8);
                acc2[j2] = __builtin_amdgcn_mfma_f32_16x16x32_bf16(af, bv, acc2[j2], 0, 0, 0);
            }
        }
        #pragma unroll
        for (int j2 = 0; j2 < 8; j2++) {
            #pragma unroll
            for (int r = 0; r < 4; r++) {
                size_t row = (size_t)(b*L_ + l0 + qd*4 + r);
                xz_out[row*1024 + n0 + j2*16 + l16] = f2bf(acc2[j2][r]);
            }
        }
    } else {
        float hd[4];
        #pragma unroll
        for (int r = 0; r < 4; r++) {
            int lrow = qd*4 + r;
            float2 mi = muv[lrow];
            float aa = 0.f;
            #pragma unroll
            for (int j = 0; j < 2; j++) {
                int col = w*32 + j*16 + l16;
                float nv = (v[j][r] - mi.x)*mi.y*lnw[col] + lnb[col];
                aa = fmaf(nv, hw[col], aa);
            }
            hd[r] = aa;
        }
        #pragma unroll
        for (int r = 0; r < 4; r++) {
            float xv = hd[r];
            xv += __shfl_xor(xv, 1); xv += __shfl_xor(xv, 2);
            xv += __shfl_xor(xv, 4); xv += __shfl_xor(xv, 8);
            if (l16 == 0) red2[w*16 + qd*4 + r].x = xv;
        }
        __syncthreads();
        if (tid < 16) {
            float xv = 0.f;
            #pragma unroll
            for (int ww = 0; ww < 8; ww++) xv += red2[ww*16 + tid].x;
            out[(size_t)(b*L_) + l0 + tid] = xv + hb[0];
        }
    }
}

extern "C" void kernel_launch(void* const* d_in, const int* in_sizes, int n_in,
                              void* d_out, int out_size, void* d_ws, size_t ws_size,
                              hipStream_t stream)
{
    const float* x    = (const float*)d_in[0];
    const float* biw  = (const float*)d_in[1];
    const float* bib  = (const float*)d_in[2];
    const float* ge   = (const float*)d_in[3];
    const float* me   = (const float*)d_in[4];
    const float* lnw  = (const float*)d_in[5];
    const float* lnb  = (const float*)d_in[6];
    const float* ipw  = (const float*)d_in[7];
    const float* cw   = (const float*)d_in[8];
    const float* cb   = (const float*)d_in[9];
    const float* xpw  = (const float*)d_in[10];
    const float* dtw  = (const float*)d_in[11];
    const float* dtb  = (const float*)d_in[12];
    const float* alog = (const float*)d_in[13];
    const float* Dv   = (const float*)d_in[14];
    const float* opw  = (const float*)d_in[15];
    const float* fw   = (const float*)d_in[16];
    const float* fb   = (const float*)d_in[17];
    const float* hw   = (const float*)d_in[18];
    const float* hb   = (const float*)d_in[19];
    float* out = (float*)d_out;

    // workspace layout (16B-aligned segments); ~50 MB
    float* ws  = (float*)d_ws;
    float* h      = ws;                                   // BLP_*DM_ f
    float* bn     = h + (size_t)BLP_*DM_;                 // B_*L_*DS_ f
    float* cn     = bn + (size_t)B_*L_*DS_;               // B_*L_*DS_ f
    float2* sa    = (float2*)(cn + (size_t)B_*L_*DS_);    // NC_*NST_ float2
    float* sinc   = (float*)(sa + (size_t)NC_*NST_);      // NC_*NST_ f
    ushort_t* aln   = (ushort_t*)(sinc + (size_t)NC_*NST_); // BLP_*DM_ us
    ushort_t* xz_bf = aln + (size_t)BLP_*DM_;             // BLP_*1024 us
    ushort_t* u_bf  = xz_bf + (size_t)BLP_*1024;          // BLP_*DI_ us
    ushort_t* dtn   = u_bf + (size_t)BLP_*DI_;            // B_*L_*DI_ us
    ushort_t* ipwb  = dtn + (size_t)B_*L_*DI_;            // NL_*1024*DM_ us
    ushort_t* opwb  = ipwb + (size_t)NL_*1024*DM_;        // NL_*DM_*DI_ us
    ushort_t* xpwb  = opwb + (size_t)NL_*DM_*DI_;         // NL_*48*512 us

    const int N0 = NL_*1024*DM_/4, N1 = NL_*DM_*DI_/4, N2 = NL_*48*512/4;
    const int conv_blocks = (N0+N1+N2 + 255)/256;
    embed_f2bf_kernel<<<BL_ + conv_blocks, 256, 0, stream>>>(
        x, biw, bib, ge, me, lnw, lnb, h, aln,
        ipw, opw, xpw, ipwb, opwb, xpwb, N0, N1, N2);

    for (int i = 0; i < NL_; i++) {
        if (i == 0) {
            conv0_inproj<<<dim3(NC_, B_), 512, 0, stream>>>(
                aln, ipwb, xz_bf,
                cw, cb, xpwb, dtw, dtb, alog,
                u_bf, bn, cn, dtn, sa);
        } else {
            conv_xproj512<<<dim3(NC_, B_), 512, 0, stream>>>(
                xz_bf, cw + i*DI_*4, cb + i*DI_, xpwb + (size_t)i*48*512,
                dtw + (size_t)i*DI_*16, dtb + i*DI_, alog + (size_t)i*DI_*DS_,
                u_bf, bn, cn, dtn, sa);
        }
        scan_phase2<<<NST_/64, 64, 0, stream>>>(sa, sinc);
        if (i < NL_-1) {
            phase3_fused<0><<<dim3(NC_, B_), 512, 0, stream>>>(
                dtn, u_bf, bn, cn, alog + (size_t)i*DI_*DS_, Dv + i*DI_,
                sinc, xz_bf, opwb + (size_t)i*DM_*DI_, h,
                lnw + (i+1)*DM_, lnb + (i+1)*DM_,
                ipwb + (size_t)(i+1)*1024*DM_, xz_bf,
                nullptr, nullptr, nullptr);
        } else {
            phase3_fused<1><<<dim3(NC_, B_), 512, 0, stream>>>(
                dtn, u_bf, bn, cn, alog + (size_t)i*DI_*DS_, Dv + i*DI_,
                sinc, xz_bf, opwb + (size_t)i*DM_*DI_, h,
                fw, fb,
                nullptr, xz_bf,
                hw, hb, out);
        }
    }
}

// Round 11
// 354.894 us; speedup vs baseline: 1.4327x; 1.1290x over previous
//
#include <hip/hip_runtime.h>
#include <math.h>

#define B_  2
#define L_  2000
#define DM_ 256
#define DI_ 512
#define DS_ 16
#define NL_ 4
#define BL_ (B_*L_)     // 4000
#define BLP_ 4096       // rows padded to multiple of 64
#define NC_  125        // scan chunks == conv strips (CL=16)
#define CL_  16
#define NST_ (B_*DI_*DS_)   // 16384 scan states

// fragment-packed weight sizes (fragments of 8 bf16)
#define NF_IP_ (NL_*64*8*64)    // 131072  ipw: t=64, ks=8
#define NF_OP_ (NL_*16*16*64)   // 65536   opw: t=16, ks=16
#define NF_XP_ (NL_*3*16*64)    // 12288   xpw: t=3,  ks=16
#define NF_TOT_ (NF_IP_ + NF_OP_ + NF_XP_)

typedef unsigned short ushort_t;
typedef __attribute__((ext_vector_type(8))) short bf16x8;
typedef __attribute__((ext_vector_type(4))) float f32x4;

__device__ __forceinline__ float siluf(float x) { return x / (1.f + __expf(-x)); }
__device__ __forceinline__ ushort_t f2bf(float x) {
    unsigned int u = __float_as_uint(x);
    return (ushort_t)((u + 0x7FFFu + ((u >> 16) & 1u)) >> 16);
}
__device__ __forceinline__ float bf2f(ushort_t v) {
    return __uint_as_float(((unsigned int)v) << 16);
}

// ---- merged embed + layer-0 LN (blocks 0..BL_-1) + fragment-pack f2bf (rest) ----
// Packed layout (per matrix W[N][K], per layer):
//   P[((t*K32 + ks)*64 + lane)*8 + e] = W[t*16 + (lane&15)][ks*32 + (lane>>4)*8 + e]
// so an MFMA B-fragment load is one contiguous 1KB wave-load.
__global__ __launch_bounds__(256) void embed_f2bf_kernel(
    const float* __restrict__ x, const float* __restrict__ biw,
    const float* __restrict__ bib, const float* __restrict__ ge,
    const float* __restrict__ me, const float* __restrict__ lnw,
    const float* __restrict__ lnb,
    float* __restrict__ h, ushort_t* __restrict__ aln,
    const float* __restrict__ ipw, const float* __restrict__ opw,
    const float* __restrict__ xpw, ushort_t* __restrict__ ipwb,
    ushort_t* __restrict__ opwb, ushort_t* __restrict__ xpwb)
{
    if (blockIdx.x < BL_) {
        __shared__ float sm[8];
        int bl = blockIdx.x, d = threadIdx.x;
        int l = bl % L_;
        float v = x[bl]*biw[d] + bib[d] + ge[(size_t)l*DM_ + d] + me[d];
        h[(size_t)bl*DM_ + d] = v;
        float s = v, q = v*v;
        #pragma unroll
        for (int o = 32; o > 0; o >>= 1) {
            s += __shfl_down(s, o);
            q += __shfl_down(q, o);
        }
        if ((d & 63) == 0) { sm[d >> 6] = s; sm[4 + (d >> 6)] = q; }
        __syncthreads();
        float sum = sm[0]+sm[1]+sm[2]+sm[3];
        float ssq = sm[4]+sm[5]+sm[6]+sm[7];
        float mu  = sum * (1.f/DM_);
        float inv = rsqrtf(fmaxf(ssq*(1.f/DM_) - mu*mu, 0.f) + 1e-5f);
        aln[(size_t)bl*DM_ + d] = f2bf((v - mu)*inv*lnw[d] + lnb[d]);
    } else {
        int i = (blockIdx.x - BL_)*256 + threadIdx.x;
        if (i >= NF_TOT_) return;
        const float* src; ushort_t* dst;
        if (i < NF_IP_) {
            int f = i;
            int li   = f >> 15;            // 32768 frags/layer
            int r    = f & 32767;
            int t    = r >> 9;             // 512 frags per t
            int rem  = r & 511;
            int ks   = rem >> 6;
            int lane = rem & 63;
            src = ipw + ((size_t)(li*1024 + t*16 + (lane & 15)))*DM_
                      + ks*32 + (lane >> 4)*8;
            dst = ipwb + (size_t)f*8;
        } else if (i < NF_IP_ + NF_OP_) {
            int f = i - NF_IP_;
            int li   = f >> 14;            // 16384 frags/layer
            int r    = f & 16383;
            int t    = r >> 10;            // 1024 frags per t
            int rem  = r & 1023;
            int ks   = rem >> 6;
            int lane = rem & 63;
            src = opw + ((size_t)(li*256 + t*16 + (lane & 15)))*DI_
                      + ks*32 + (lane >> 4)*8;
            dst = opwb + (size_t)f*8;
        } else {
            int f = i - NF_IP_ - NF_OP_;
            int li   = f / 3072;           // 3072 frags/layer
            int r    = f % 3072;
            int t    = r >> 10;
            int rem  = r & 1023;
            int ks   = rem >> 6;
            int lane = rem & 63;
            src = xpw + ((size_t)(li*48 + t*16 + (lane & 15)))*DI_
                      + ks*32 + (lane >> 4)*8;
            dst = xpwb + (size_t)f*8;
        }
        float4 v0 = *(const float4*)src;
        float4 v1 = *(const float4*)(src + 4);
        __align__(16) ushort_t o[8];
        o[0] = f2bf(v0.x); o[1] = f2bf(v0.y); o[2] = f2bf(v0.z); o[3] = f2bf(v0.w);
        o[4] = f2bf(v1.x); o[5] = f2bf(v1.y); o[6] = f2bf(v1.z); o[7] = f2bf(v1.w);
        *(uint4*)dst = *(const uint4*)o;
    }
}

// ---- bf16 MFMA GEMM: xz = aln * ipw^T (layer 0); B read packed from L2 ----
__global__ __launch_bounds__(256) void gemm_bf(
    const ushort_t* __restrict__ A, const ushort_t* __restrict__ Wp,
    ushort_t* __restrict__ C)
{
    __shared__ ushort_t a_s[128*64];
    const int r0 = blockIdx.x*128, c0 = blockIdx.y*128;
    const int tid = threadIdx.x;
    const int lane = tid & 63, w = tid >> 6;
    const int wm = (w & 1)*64, wn = (w >> 1)*64;
    const int qd = lane >> 4, l16 = lane & 15;
    const int tb = (c0 + wn) >> 4;          // B tile base for this wave
    f32x4 acc[4][4] = {};
    for (int kc = 0; kc < DM_; kc += 64) {
        #pragma unroll
        for (int q = 0; q < 4; q++) {
            int ch = tid + 256*q;           // 0..1023
            int row = ch >> 3, col8 = (ch & 7)*8;
            *(bf16x8*)&a_s[row*64 + col8] =
                *(const bf16x8*)(A + (size_t)(r0 + row)*DM_ + kc + col8);
        }
        __syncthreads();
        #pragma unroll
        for (int ks = 0; ks < 2; ks++) {
            int ksg = (kc >> 5) + ks;
            bf16x8 af[4], bf[4];
            #pragma unroll
            for (int i = 0; i < 4; i++)
                af[i] = *(const bf16x8*)&a_s[(wm + i*16 + l16)*64 + ks*32 + qd*8];
            #pragma unroll
            for (int j = 0; j < 4; j++)
                bf[j] = *(const bf16x8*)(Wp +
                    (((size_t)(tb + j)*8 + ksg)*64 + lane)*8);
            #pragma unroll
            for (int i = 0; i < 4; i++) {
                #pragma unroll
                for (int j = 0; j < 4; j++)
                    acc[i][j] = __builtin_amdgcn_mfma_f32_16x16x32_bf16(
                        af[i], bf[j], acc[i][j], 0, 0, 0);
            }
        }
        __syncthreads();
    }
    #pragma unroll
    for (int i = 0; i < 4; i++) {
        #pragma unroll
        for (int j = 0; j < 4; j++) {
            #pragma unroll
            for (int r = 0; r < 4; r++) {
                int row = r0 + wm + i*16 + qd*4 + r;
                int col = c0 + wn + j*16 + l16;
                C[(size_t)row*1024 + col] = f2bf(acc[i][j][r]);
            }
        }
    }
}

// ---- conv(4)+silu + x_proj MFMA (packed) + dt_proj + scan phase1 ----
__global__ __launch_bounds__(512) void conv_xproj512(
    const ushort_t* __restrict__ xz, const float* __restrict__ cw,
    const float* __restrict__ cb, const ushort_t* __restrict__ XWp,
    const float* __restrict__ DTW, const float* __restrict__ DTB,
    const float* __restrict__ Alog,
    ushort_t* __restrict__ u_bf, float* __restrict__ bn,
    float* __restrict__ cn, ushort_t* __restrict__ dtn,
    float2* __restrict__ sa)
{
    __shared__ ushort_t xs[19][520];
    __shared__ ushort_t us[16][520];
    __shared__ float ps[8*768];
    __shared__ float dtr_s[16][16];
    const int c = blockIdx.x, b = blockIdx.y, l0 = c*CL_;
    const int tid = threadIdx.x;
    const int lane = tid & 63, w = tid >> 6;
    const int qd = lane >> 4, l16 = lane & 15;
    for (int f = tid; f < 19*64; f += 512) {
        int row = f >> 6, c8 = (f & 63)*8;
        int l = l0 - 3 + row;
        uint4 v = {0u,0u,0u,0u};
        if (l >= 0) v = *(const uint4*)(xz + (size_t)(b*L_ + l)*1024 + c8);
        *(uint4*)&xs[row][c8] = v;
    }
    __syncthreads();
    {
        int ch = tid;
        float4 wv = *(const float4*)(cw + ch*4);
        float bias = cb[ch];
        float x0 = bf2f(xs[0][ch]);
        float x1 = bf2f(xs[1][ch]);
        float x2 = bf2f(xs[2][ch]);
        #pragma unroll
        for (int j = 0; j < 16; j++) {
            float x3 = bf2f(xs[3 + j][ch]);
            float v = fmaf(x0, wv.x, fmaf(x1, wv.y, fmaf(x2, wv.z, fmaf(x3, wv.w, bias))));
            us[j][ch] = f2bf(siluf(v));
            x0 = x1; x1 = x2; x2 = x3;
        }
    }
    __syncthreads();
    for (int f = tid; f < 16*64; f += 512) {
        int row = f >> 6, c8 = (f & 63)*8;
        *(uint4*)(u_bf + (size_t)(b*L_ + l0 + row)*512 + c8) =
            *(const uint4*)&us[row][c8];
    }
    f32x4 acc[3] = {};
    #pragma unroll
    for (int st = 0; st < 2; st++) {
        int k = w*64 + st*32 + qd*8;
        int ksg = w*2 + st;                 // k / 32
        bf16x8 af = *(const bf16x8*)&us[l16][k];
        #pragma unroll
        for (int j = 0; j < 3; j++) {
            bf16x8 bv = *(const bf16x8*)(XWp +
                (((size_t)j*16 + ksg)*64 + lane)*8);
            acc[j] = __builtin_amdgcn_mfma_f32_16x16x32_bf16(af, bv, acc[j], 0, 0, 0);
        }
    }
    #pragma unroll
    for (int j = 0; j < 3; j++)
        #pragma unroll
        for (int r = 0; r < 4; r++)
            ps[w*768 + (qd*4 + r)*48 + j*16 + l16] = acc[j][r];
    __syncthreads();
    for (int e = tid; e < 768; e += 512) {
        float v = ps[e] + ps[768+e] + ps[1536+e] + ps[2304+e]
                + ps[3072+e] + ps[3840+e] + ps[4608+e] + ps[5376+e];
        ps[e] = v;
    }
    __syncthreads();
    if (tid < 256) {
        int row = tid >> 4, n = tid & 15;
        dtr_s[row][n] = ps[row*48 + n];
        size_t base = ((size_t)(b*L_) + l0 + row)*DS_ + n;
        bn[base] = ps[row*48 + 16 + n];
        cn[base] = ps[row*48 + 32 + n];
    }
    __syncthreads();
    {
        const int d = tid;
        float wreg[16];
        const float4* wp = (const float4*)(DTW + (size_t)d*16);
        #pragma unroll
        for (int k4 = 0; k4 < 4; k4++) {
            float4 v = wp[k4];
            wreg[4*k4+0] = v.x; wreg[4*k4+1] = v.y;
            wreg[4*k4+2] = v.z; wreg[4*k4+3] = v.w;
        }
        float bias = DTB[d];
        float dtv[16];
        #pragma unroll
        for (int r = 0; r < 16; r++) {
            float a = bias;
            #pragma unroll
            for (int k = 0; k < 16; k++) a = fmaf(dtr_s[r][k], wreg[k], a);
            float dt = a > 20.f ? a : log1pf(__expf(a));
            ushort_t dtb16 = f2bf(dt);
            dtn[((size_t)(b*L_) + l0 + r)*DI_ + d] = dtb16;
            dtv[r] = bf2f(dtb16);
        }
        float Ac[DS_], s[DS_], ap[DS_];
        const float* ar = Alog + (size_t)d*DS_;
        #pragma unroll
        for (int n = 0; n < DS_; n++) { Ac[n] = -__expf(ar[n]); s[n] = 0.f; ap[n] = 1.f; }
        #pragma unroll
        for (int l = 0; l < 16; l++) {
            float dt = dtv[l];
            float u  = bf2f(us[l][d]);
            float dtu = dt*u;
            #pragma unroll
            for (int n = 0; n < DS_; n++) {
                float e = __expf(dt*Ac[n]);
                s[n] = fmaf(e, s[n], dtu*ps[l*48 + 16 + n]);
                ap[n] *= e;
            }
        }
        size_t ib = (((size_t)c*B_ + b)*DI_ + d)*DS_;
        float2* sap = sa + ib;
        #pragma unroll
        for (int k = 0; k < 8; k++)
            *(float4*)&sap[2*k] = make_float4(s[2*k], ap[2*k], s[2*k+1], ap[2*k+1]);
    }
}

// ---- phase2: cross-chunk exclusive prefix ----
__global__ __launch_bounds__(64) void scan_phase2(
    const float2* __restrict__ sa, float* __restrict__ sinc)
{
    const int t = blockIdx.x*64 + threadIdx.x;
    float s = 0.f;
    for (int g = 0; g < 5; g++) {
        float2 v[25];
        #pragma unroll
        for (int i = 0; i < 25; i++)
            v[i] = sa[(size_t)(g*25 + i)*NST_ + t];
        #pragma unroll
        for (int i = 0; i < 25; i++) {
            sinc[(size_t)(g*25 + i)*NST_ + t] = s;
            s = fmaf(v[i].y, s, v[i].x);
        }
    }
}

// ---- fused phase3 + out_proj + residual + LN + (next in_proj | head) ----
// opw/ipw read fragment-packed (coalesced 1KB wave-loads).
template<int LAST>
__global__ __launch_bounds__(512) void phase3_fused(
    const ushort_t* __restrict__ dtn, const ushort_t* __restrict__ u_bf,
    const float* __restrict__ bn, const float* __restrict__ cn,
    const float* __restrict__ Alog, const float* __restrict__ Dv,
    const float* __restrict__ sinc, const ushort_t* __restrict__ xz,
    const ushort_t* __restrict__ opw, float* __restrict__ h,
    const float* __restrict__ lnw, const float* __restrict__ lnb,
    const ushort_t* __restrict__ ipw, ushort_t* __restrict__ xz_out,
    const float* __restrict__ hw, const float* __restrict__ hb,
    float* __restrict__ out)
{
    __shared__ float b_sh[CL_*DS_];
    __shared__ float c_sh[CL_*DS_];
    __shared__ ushort_t ys[16][520];
    __shared__ union { ushort_t dt_t[16][520]; ushort_t z_t[16][520]; } T0;
    __shared__ union { ushort_t u_t[16][520];  ushort_t a_sh[16][264]; } T1;
    __shared__ float2 red2[128];
    __shared__ float2 muv[16];
    const int c = blockIdx.x, b = blockIdx.y, l0 = c*CL_;
    const int tid = threadIdx.x;
    const int w = tid >> 6, lane = tid & 63;
    const int qd = lane >> 4, l16 = lane & 15;
    {
        int f = tid & 255;
        size_t src = ((size_t)(b*L_) + l0)*DS_ + f;
        if (tid < 256) b_sh[f] = bn[src];
        else           c_sh[f] = cn[src];
    }
    {
        const int r = tid >> 5, cb16 = (tid & 31)*16;
        size_t rb = ((size_t)(b*L_) + l0 + r)*DI_ + cb16;
        *(uint4*)&T0.dt_t[r][cb16]     = *(const uint4*)(dtn + rb);
        *(uint4*)&T0.dt_t[r][cb16 + 8] = *(const uint4*)(dtn + rb + 8);
        *(uint4*)&T1.u_t[r][cb16]      = *(const uint4*)(u_bf + rb);
        *(uint4*)&T1.u_t[r][cb16 + 8]  = *(const uint4*)(u_bf + rb + 8);
    }
    const int d = tid;
    float Ac[DS_], s[DS_];
    {
        const float* ar = Alog + (size_t)d*DS_;
        #pragma unroll
        for (int n = 0; n < DS_; n++) Ac[n] = -__expf(ar[n]);
        size_t base = (((size_t)c*B_ + b)*DI_ + d)*DS_;
        #pragma unroll
        for (int n4 = 0; n4 < 4; n4++)
            *(float4*)&s[4*n4] = *(const float4*)(sinc + base + 4*n4);
    }
    const float Dd = Dv[d];
    __syncthreads();
    float y_reg[CL_];
    #pragma unroll
    for (int l = 0; l < CL_; l++) {
        float dt = bf2f(T0.dt_t[l][d]);
        float u  = bf2f(T1.u_t[l][d]);
        float dtu = dt*u;
        float y = u*Dd;
        #pragma unroll
        for (int n = 0; n < DS_; n++) {
            float e = __expf(dt*Ac[n]);
            s[n] = fmaf(e, s[n], dtu*b_sh[l*DS_ + n]);
            y = fmaf(s[n], c_sh[l*DS_ + n], y);
        }
        y_reg[l] = y;
    }
    __syncthreads();
    {
        const int r = tid >> 5, cb16 = (tid & 31)*16;
        size_t rb = ((size_t)(b*L_) + l0 + r)*1024 + 512 + cb16;
        *(uint4*)&T0.z_t[r][cb16]     = *(const uint4*)(xz + rb);
        *(uint4*)&T0.z_t[r][cb16 + 8] = *(const uint4*)(xz + rb + 8);
    }
    __syncthreads();
    #pragma unroll
    for (int l = 0; l < CL_; l++)
        ys[l][d] = f2bf(y_reg[l] * siluf(bf2f(T0.z_t[l][d])));
    __syncthreads();
    // --- out_proj MFMA: wave w covers cols w*32..w*32+31; packed B ---
    f32x4 acc[2] = {};
    #pragma unroll
    for (int ks = 0; ks < 16; ks++) {
        bf16x8 af = *(const bf16x8*)&ys[l16][ks*32 + qd*8];
        #pragma unroll
        for (int j = 0; j < 2; j++) {
            bf16x8 bv = *(const bf16x8*)(opw +
                (((size_t)(w*2 + j)*16 + ks)*64 + lane)*8);
            acc[j] = __builtin_amdgcn_mfma_f32_16x16x32_bf16(af, bv, acc[j], 0, 0, 0);
        }
    }
    float v[2][4];
    #pragma unroll
    for (int r = 0; r < 4; r++) {
        int lrow = qd*4 + r;
        size_t gr = (size_t)(b*L_ + l0 + lrow);
        float sm = 0.f, sq = 0.f;
        #pragma unroll
        for (int j = 0; j < 2; j++) {
            int col = w*32 + j*16 + l16;
            size_t idx = gr*DM_ + col;
            float vv = h[idx] + acc[j][r];
            if (!LAST) h[idx] = vv;
            v[j][r] = vv;
            sm += vv; sq += vv*vv;
        }
        sm += __shfl_xor(sm, 1); sq += __shfl_xor(sq, 1);
        sm += __shfl_xor(sm, 2); sq += __shfl_xor(sq, 2);
        sm += __shfl_xor(sm, 4); sq += __shfl_xor(sq, 4);
        sm += __shfl_xor(sm, 8); sq += __shfl_xor(sq, 8);
        if (l16 == 0) red2[w*16 + lrow] = make_float2(sm, sq);
    }
    __syncthreads();
    if (tid < 16) {
        float sm = 0.f, sq = 0.f;
        #pragma unroll
        for (int ww = 0; ww < 8; ww++) {
            float2 t = red2[ww*16 + tid];
            sm += t.x; sq += t.y;
        }
        float mu  = sm*(1.f/DM_);
        float inv = rsqrtf(fmaxf(sq*(1.f/DM_) - mu*mu, 0.f) + 1e-5f);
        muv[tid] = make_float2(mu, inv);
    }
    __syncthreads();
    if (!LAST) {
        #pragma unroll
        for (int r = 0; r < 4; r++) {
            int lrow = qd*4 + r;
            float2 mi = muv[lrow];
            #pragma unroll
            for (int j = 0; j < 2; j++) {
                int col = w*32 + j*16 + l16;
                T1.a_sh[lrow][col] = f2bf((v[j][r] - mi.x)*mi.y*lnw[col] + lnb[col]);
            }
        }
        __syncthreads();
        f32x4 acc2[8] = {};
        const int n0 = w*128;
        #pragma unroll
        for (int ks = 0; ks < 8; ks++) {
            bf16x8 af = *(const bf16x8*)&T1.a_sh[l16][ks*32 + qd*8];
            #pragma unroll
            for (int j2 = 0; j2 < 8; j2++) {
                bf16x8 bv = *(const bf16x8*)(ipw +
                    (((size_t)(w*8 + j2)*8 + ks)*64 + lane)*8);
                acc2[j2] = __builtin_amdgcn_mfma_f32_16x16x32_bf16(af, bv, acc2[j2], 0, 0, 0);
            }
        }
        #pragma unroll
        for (int j2 = 0; j2 < 8; j2++) {
            #pragma unroll
            for (int r = 0; r < 4; r++) {
                size_t row = (size_t)(b*L_ + l0 + qd*4 + r);
                xz_out[row*1024 + n0 + j2*16 + l16] = f2bf(acc2[j2][r]);
            }
        }
    } else {
        float hd[4];
        #pragma unroll
        for (int r = 0; r < 4; r++) {
            int lrow = qd*4 + r;
            float2 mi = muv[lrow];
            float aa = 0.f;
            #pragma unroll
            for (int j = 0; j < 2; j++) {
                int col = w*32 + j*16 + l16;
                float nv = (v[j][r] - mi.x)*mi.y*lnw[col] + lnb[col];
                aa = fmaf(nv, hw[col], aa);
            }
            hd[r] = aa;
        }
        #pragma unroll
        for (int r = 0; r < 4; r++) {
            float xv = hd[r];
            xv += __shfl_xor(xv, 1); xv += __shfl_xor(xv, 2);
            xv += __shfl_xor(xv, 4); xv += __shfl_xor(xv, 8);
            if (l16 == 0) red2[w*16 + qd*4 + r].x = xv;
        }
        __syncthreads();
        if (tid < 16) {
            float xv = 0.f;
            #pragma unroll
            for (int ww = 0; ww < 8; ww++) xv += red2[ww*16 + tid].x;
            out[(size_t)(b*L_) + l0 + tid] = xv + hb[0];
        }
    }
}

extern "C" void kernel_launch(void* const* d_in, const int* in_sizes, int n_in,
                              void* d_out, int out_size, void* d_ws, size_t ws_size,
                              hipStream_t stream)
{
    const float* x    = (const float*)d_in[0];
    const float* biw  = (const float*)d_in[1];
    const float* bib  = (const float*)d_in[2];
    const float* ge   = (const float*)d_in[3];
    const float* me   = (const float*)d_in[4];
    const float* lnw  = (const float*)d_in[5];
    const float* lnb  = (const float*)d_in[6];
    const float* ipw  = (const float*)d_in[7];
    const float* cw   = (const float*)d_in[8];
    const float* cb   = (const float*)d_in[9];
    const float* xpw  = (const float*)d_in[10];
    const float* dtw  = (const float*)d_in[11];
    const float* dtb  = (const float*)d_in[12];
    const float* alog = (const float*)d_in[13];
    const float* Dv   = (const float*)d_in[14];
    const float* opw  = (const float*)d_in[15];
    const float* fw   = (const float*)d_in[16];
    const float* fb   = (const float*)d_in[17];
    const float* hw   = (const float*)d_in[18];
    const float* hb   = (const float*)d_in[19];
    float* out = (float*)d_out;

    // workspace layout (16B-aligned segments); ~50 MB
    float* ws  = (float*)d_ws;
    float* h      = ws;                                   // BLP_*DM_ f
    float* bn     = h + (size_t)BLP_*DM_;                 // B_*L_*DS_ f
    float* cn     = bn + (size_t)B_*L_*DS_;               // B_*L_*DS_ f
    float2* sa    = (float2*)(cn + (size_t)B_*L_*DS_);    // NC_*NST_ float2
    float* sinc   = (float*)(sa + (size_t)NC_*NST_);      // NC_*NST_ f
    ushort_t* aln   = (ushort_t*)(sinc + (size_t)NC_*NST_); // BLP_*DM_ us
    ushort_t* xz_bf = aln + (size_t)BLP_*DM_;             // BLP_*1024 us
    ushort_t* u_bf  = xz_bf + (size_t)BLP_*1024;          // BLP_*DI_ us
    ushort_t* dtn   = u_bf + (size_t)BLP_*DI_;            // B_*L_*DI_ us
    ushort_t* ipwb  = dtn + (size_t)B_*L_*DI_;            // NL_*1024*DM_ us (packed)
    ushort_t* opwb  = ipwb + (size_t)NL_*1024*DM_;        // NL_*DM_*DI_ us (packed)
    ushort_t* xpwb  = opwb + (size_t)NL_*DM_*DI_;         // NL_*48*512 us (packed)

    const int conv_blocks = (NF_TOT_ + 255)/256;
    embed_f2bf_kernel<<<BL_ + conv_blocks, 256, 0, stream>>>(
        x, biw, bib, ge, me, lnw, lnb, h, aln,
        ipw, opw, xpw, ipwb, opwb, xpwb);

    gemm_bf<<<dim3(BLP_/128, 1024/128), 256, 0, stream>>>(
        aln, ipwb, xz_bf);

    for (int i = 0; i < NL_; i++) {
        conv_xproj512<<<dim3(NC_, B_), 512, 0, stream>>>(
            xz_bf, cw + i*DI_*4, cb + i*DI_, xpwb + (size_t)i*48*512,
            dtw + (size_t)i*DI_*16, dtb + i*DI_, alog + (size_t)i*DI_*DS_,
            u_bf, bn, cn, dtn, sa);
        scan_phase2<<<NST_/64, 64, 0, stream>>>(sa, sinc);
        if (i < NL_-1) {
            phase3_fused<0><<<dim3(NC_, B_), 512, 0, stream>>>(
                dtn, u_bf, bn, cn, alog + (size_t)i*DI_*DS_, Dv + i*DI_,
                sinc, xz_bf, opwb + (size_t)i*DM_*DI_, h,
                lnw + (i+1)*DM_, lnb + (i+1)*DM_,
                ipwb + (size_t)(i+1)*1024*DM_, xz_bf,
                nullptr, nullptr, nullptr);
        } else {
            phase3_fused<1><<<dim3(NC_, B_), 512, 0, stream>>>(
                dtn, u_bf, bn, cn, alog + (size_t)i*DI_*DS_, Dv + i*DI_,
                sinc, xz_bf, opwb + (size_t)i*DM_*DI_, h,
                fw, fb,
                nullptr, xz_bf,
                hw, hb, out);
        }
    }
}